// Round 2
// baseline (218.696 us; speedup 1.0000x reference)
//
#include <hip/hip_runtime.h>
#include <hip/hip_bf16.h>
#include <math.h>

#define B_   2
#define N_   2000
#define T_   24
#define NX_  8
#define H_   64
#define G_   (B_*T_)        // 48 graphs
#define E_   32000
#define BN_  (B_*N_)        // 4000 sequences
#define TH_  (T_*H_)        // 1536
#define NTH_ (N_*T_*H_)     // 3072000
#define GNH_ (G_*N_*H_)     // 6144000
#define NPARAM_ 43340       // canonical fp32 param elements (x excluded)
#define NPARAM_PAD_ 43392
#define XSTRIDE 1568        // per-seq x row (bf16 elems): 3136B; 3136/16 ≡ 4 (mod 8) -> quad=(4cc+q)%8, <=2-way
#define HPAD 96             // h row pad (bf16 elems): 192B; 192/16 ≡ 4 (mod 8) -> <=2-way on ds_read_b128
#define DEGCAP 64           // slot capacity per dst node (max binomial deg ~35)

using bf16 = __hip_bfloat16;
typedef short bf16x8 __attribute__((ext_vector_type(8)));
typedef float f32x4  __attribute__((ext_vector_type(4)));

__device__ __forceinline__ float uasf(unsigned u){ return __uint_as_float(u); }
__device__ __forceinline__ float wave_sum(float v){
  #pragma unroll
  for (int o = 32; o > 0; o >>= 1) v += __shfl_xor(v, o, 64);
  return v;
}
__device__ __forceinline__ float fastrcp(float x){ return __builtin_amdgcn_rcpf(x); }
__device__ __forceinline__ float sigf(float x){ return fastrcp(1.f + __expf(-x)); }
__device__ __forceinline__ float tanhfast(float x){ return 1.f - 2.f*fastrcp(1.f + __expf(2.f*x)); }
__device__ __forceinline__ float gelu_exact(float x){ return 0.5f*x*(1.f + erff(x*0.70710678118654752f)); }
__device__ __forceinline__ unsigned f2bf_rtn(float f){
  unsigned u = __float_as_uint(f);
  u += 0x7fffu + ((u >> 16) & 1u);
  return u >> 16;
}
// static-index 4-way select: q per-lane runtime, indices compile-time (rule #20 safe)
__device__ __forceinline__ float sel4(f32x4 v, int q){
  float a = (q & 1) ? v[1] : v[0];
  float b = (q & 1) ? v[3] : v[2];
  return (q & 2) ? b : a;
}
__device__ __forceinline__ bf16x8 pack8(float4 a, float4 b){
  bf16x8 v;
  v[0]=(short)f2bf_rtn(a.x); v[1]=(short)f2bf_rtn(a.y);
  v[2]=(short)f2bf_rtn(a.z); v[3]=(short)f2bf_rtn(a.w);
  v[4]=(short)f2bf_rtn(b.x); v[5]=(short)f2bf_rtn(b.y);
  v[6]=(short)f2bf_rtn(b.z); v[7]=(short)f2bf_rtn(b.w);
  return v;
}

// ---------- prep: dtype detect + param convert + cnt zero + Wc fold, ONE dispatch ----------
struct ConvArgs {
  const void* src[18];
  int off[19];
};
__global__ __launch_bounds__(256) void prep_kernel(
    ConvArgs a, const unsigned* __restrict__ xw,
    float* __restrict__ dst, int* __restrict__ flag,
    int* __restrict__ cnt_g,
    float* __restrict__ wc, float* __restrict__ bc){
  __shared__ int scnt;
  int tid = threadIdx.x;
  if (tid == 0) scnt = 0;
  __syncthreads();
  int c = 0;
  for (int i = tid; i < 4096; i += 256){
    unsigned e = (xw[i] >> 7) & 0xffu;
    if (e >= 100u && e <= 140u) c++;
  }
  atomicAdd(&scnt, c);
  __syncthreads();
  int isbf = (scnt > 3276) ? 1 : 0;
  int bid = blockIdx.x;

  if (bid < 170){
    if (bid == 0 && tid == 0) *flag = isbf;
    int i = bid*256 + tid;
    if (i < NPARAM_){
      int seg = 0;
      while (i >= a.off[seg+1]) seg++;
      int j = i - a.off[seg];
      float v;
      if (isbf) v = uasf(((unsigned)((const unsigned short*)a.src[seg])[j]) << 16);
      else      v = ((const float*)a.src[seg])[j];
      dst[i] = v;
    }
  } else if (bid == 170){
    for (int i = tid; i < N_; i += 256) cnt_g[i] = 0;
  } else {
    // blocks 171..179: Wc = fcW @ g1W (512 outs) + bc = fcb @ g1W (64 outs)
    int lane = tid & 63, wave = tid >> 6;
    int b = bid - 171;                   // 0..8
    const unsigned short* fcWu = (const unsigned short*)a.src[0];
    const unsigned short* fcbu = (const unsigned short*)a.src[1];
    const unsigned short* g1Wu = (const unsigned short*)a.src[2];
    const float* fcWf = (const float*)a.src[0];
    const float* fcbf = (const float*)a.src[1];
    const float* g1Wf = (const float*)a.src[2];
    #pragma unroll
    for (int s = 0; s < 16; ++s){
      int o = b*64 + wave*16 + s;        // 0..575
      int r = o >> 6;                    // 0..8 (8 == bias row)
      int n = o & 63;
      float fa, fb;
      if (isbf){
        fa = (r < 8) ? uasf(((unsigned)fcWu[r*64 + lane]) << 16)
                     : uasf(((unsigned)fcbu[lane]) << 16);
        fb = uasf(((unsigned)g1Wu[lane*64 + n]) << 16);
      } else {
        fa = (r < 8) ? fcWf[r*64 + lane] : fcbf[lane];
        fb = g1Wf[lane*64 + n];
      }
      float sv = wave_sum(fa * fb);
      if (lane == 0){
        if (r < 8) wc[r*64 + n] = sv;
        else       bc[n] = sv;
      }
    }
  }
}

// ---------- GAT1 fused: edge-table build (blocks 0..124) + h = x @ Wc + bc via MFMA ----------
__global__ __launch_bounds__(256) void gat_h1_fused_kernel(
    const void* __restrict__ xraw, const int* __restrict__ flag,
    const int* __restrict__ esrc, const int* __restrict__ edst,
    int* __restrict__ cnt_g, int* __restrict__ slot,
    const float* __restrict__ wc, const float* __restrict__ bc,
    const float* __restrict__ asrc, const float* __restrict__ adst,
    unsigned short* __restrict__ hbuf, float* __restrict__ es, float* __restrict__ ed){
  if (blockIdx.x < 125){
    int e = blockIdx.x*256 + threadIdx.x;      // exactly covers E_=32000
    int d = edst[e];
    int pos = atomicAdd(&cnt_g[d], 1);
    if (pos < DEGCAP) slot[(d << 6) + pos] = esrc[e];
  }
  int lane = threadIdx.x & 63, wave = threadIdx.x >> 6;
  int q = lane >> 4, c = lane & 15;
  int isbf = *flag;
  bf16x8 Bf[4];                       // B[n=c][k=q*8+j]; only q==0 rows of Wc nonzero
  #pragma unroll
  for (int nt = 0; nt < 4; ++nt){
    bf16x8 v;
    #pragma unroll
    for (int j = 0; j < 8; ++j)
      v[j] = (q == 0) ? (short)f2bf_rtn(wc[j*64 + nt*16 + c]) : (short)0;
    Bf[nt] = v;
  }
  float bcv[4];
  #pragma unroll
  for (int nt = 0; nt < 4; ++nt) bcv[nt] = bc[nt*16 + c];
  float aS[4], aD[4];
  #pragma unroll
  for (int nt = 0; nt < 4; ++nt){ aS[nt] = asrc[nt*16+c]; aD[nt] = adst[nt*16+c]; }

  int w = blockIdx.x*4 + wave;        // 750*4 = 3000 waves, 2 tiles each
  #pragma unroll
  for (int it = 0; it < 2; ++it){
    int tile = w*2 + it;
    int p0 = tile*16;
    int g  = p0 / N_, n0 = p0 - g*N_;
    int bb = g / T_,  tt = g - bb*T_;
    bf16x8 A0;
    #pragma unroll
    for (int j = 0; j < 8; ++j) A0[j] = 0;
    if (q == 0){
      size_t rowelt = ((size_t)(bb*N_ + n0 + c)*T_ + tt)*NX_;
      if (isbf){
        A0 = *(const bf16x8*)((const unsigned short*)xraw + rowelt);
      } else {
        const float4* xr4 = (const float4*)((const float*)xraw + rowelt);
        A0 = pack8(xr4[0], xr4[1]);
      }
    }
    f32x4 acc[4];
    #pragma unroll
    for (int nt = 0; nt < 4; ++nt){ acc[nt][0]=bcv[nt]; acc[nt][1]=bcv[nt]; acc[nt][2]=bcv[nt]; acc[nt][3]=bcv[nt]; }
    #pragma unroll
    for (int nt = 0; nt < 4; ++nt) acc[nt] = __builtin_amdgcn_mfma_f32_16x16x32_bf16(A0, Bf[nt], acc[nt], 0, 0, 0);

    #pragma unroll
    for (int nt = 0; nt < 4; ++nt){
      #pragma unroll
      for (int r = 0; r < 4; ++r)
        hbuf[(size_t)(p0 + q*4 + r)*H_ + nt*16 + c] = (unsigned short)f2bf_rtn(acc[nt][r]);
    }
    #pragma unroll
    for (int r = 0; r < 4; ++r){
      float e1 = acc[0][r]*aS[0] + acc[1][r]*aS[1] + acc[2][r]*aS[2] + acc[3][r]*aS[3];
      float e2 = acc[0][r]*aD[0] + acc[1][r]*aD[1] + acc[2][r]*aD[2] + acc[3][r]*aD[3];
      #pragma unroll
      for (int o = 8; o > 0; o >>= 1){
        e1 += __shfl_xor(e1, o, 64);
        e2 += __shfl_xor(e2, o, 64);
      }
      if (c == 0){
        es[p0 + q*4 + r] = e1;
        ed[p0 + q*4 + r] = e2;
      }
    }
  }
}

// ---------- GAT2 h = gout1(bf16) @ W via MFMA (scrambled raw-reshape reads) ----------
__global__ __launch_bounds__(256) void gat_h2_mfma_kernel(
    const unsigned short* __restrict__ xinb, const float* __restrict__ W,
    const float* __restrict__ asrc, const float* __restrict__ adst,
    unsigned short* __restrict__ hbuf, float* __restrict__ es, float* __restrict__ ed){
  int lane = threadIdx.x & 63, wave = threadIdx.x >> 6;
  int q = lane >> 4, c = lane & 15;
  bf16x8 Bf[4][2];
  #pragma unroll
  for (int nt = 0; nt < 4; ++nt){
    #pragma unroll
    for (int ks = 0; ks < 2; ++ks){
      bf16x8 v;
      #pragma unroll
      for (int j = 0; j < 8; ++j)
        v[j] = (short)f2bf_rtn(W[(ks*32 + q*8 + j)*H_ + nt*16 + c]);
      Bf[nt][ks] = v;
    }
  }
  float aS[4], aD[4];
  #pragma unroll
  for (int nt = 0; nt < 4; ++nt){ aS[nt] = asrc[nt*16+c]; aD[nt] = adst[nt*16+c]; }

  int w = blockIdx.x*4 + wave;
  #pragma unroll
  for (int it = 0; it < 2; ++it){
    int tile = w*2 + it;
    int p0 = tile*16;
    int p  = p0 + c;
    int g = p / N_, n = p - g*N_;
    int bb = g / T_, t = g - bb*T_;
    const unsigned short* xr = xinb + (size_t)bb*NTH_ + (size_t)n*TH_ + (size_t)t*H_;
    bf16x8 A0 = *(const bf16x8*)(xr + q*8);
    bf16x8 A1 = *(const bf16x8*)(xr + 32 + q*8);

    f32x4 acc[4];
    #pragma unroll
    for (int nt = 0; nt < 4; ++nt){ acc[nt][0]=0.f; acc[nt][1]=0.f; acc[nt][2]=0.f; acc[nt][3]=0.f; }
    #pragma unroll
    for (int nt = 0; nt < 4; ++nt) acc[nt] = __builtin_amdgcn_mfma_f32_16x16x32_bf16(A0, Bf[nt][0], acc[nt], 0, 0, 0);
    #pragma unroll
    for (int nt = 0; nt < 4; ++nt) acc[nt] = __builtin_amdgcn_mfma_f32_16x16x32_bf16(A1, Bf[nt][1], acc[nt], 0, 0, 0);

    #pragma unroll
    for (int nt = 0; nt < 4; ++nt){
      #pragma unroll
      for (int r = 0; r < 4; ++r)
        hbuf[(size_t)(p0 + q*4 + r)*H_ + nt*16 + c] = (unsigned short)f2bf_rtn(acc[nt][r]);
    }
    #pragma unroll
    for (int r = 0; r < 4; ++r){
      float e1 = acc[0][r]*aS[0] + acc[1][r]*aS[1] + acc[2][r]*aS[2] + acc[3][r]*aS[3];
      float e2 = acc[0][r]*aD[0] + acc[1][r]*aD[1] + acc[2][r]*aD[2] + acc[3][r]*aD[3];
      #pragma unroll
      for (int o = 8; o > 0; o >>= 1){
        e1 += __shfl_xor(e1, o, 64);
        e2 += __shfl_xor(e2, o, 64);
      }
      if (c == 0){
        es[p0 + q*4 + r] = e1;
        ed[p0 + q*4 + r] = e2;
      }
    }
  }
}

// ---------- GAT aggregate: 4 (g,d)/wave, 4 chan/lane uint2 gathers, bf16 output ----------
__global__ __launch_bounds__(256) void gat_agg_kernel(
    const unsigned short* __restrict__ hbuf, const float* __restrict__ es, const float* __restrict__ ed,
    const int* __restrict__ cnt_g, const int* __restrict__ slot,
    const float* __restrict__ bias, unsigned short* __restrict__ goutb){
  int lane = threadIdx.x & 63, wave = threadIdx.x >> 6;
  int qd = lane >> 4, ln = lane & 15;
  int gd = (blockIdx.x*4 + wave)*4 + qd;   // 6000 blocks -> 96000 pairs
  int g = gd / N_, d = gd - g*N_;
  int start = d << 6;
  int deg = min(cnt_g[d], DEGCAP);
  const float* esg = es + (size_t)g*N_;
  float edv = ed[(size_t)g*N_ + d];
  const char* hg = (const char*)(hbuf + (size_t)g*N_*H_);
  unsigned lanoff = ((unsigned)ln) << 3;   // 8 B per lane = 4 bf16 channels
  int hbase = qd << 4;
  int dm = deg;                             // wave-uniform max degree over 4 groups
  dm = max(dm, __shfl_xor(dm, 16, 64));
  dm = max(dm, __shfl_xor(dm, 32, 64));
  int NC = (dm + 15) >> 4;                  // chunks of 16, <=4

  int svk[4]; float sck[4];
  #pragma unroll
  for (int k = 0; k < 4; ++k){ svk[k] = 0; sck[k] = -1e30f; }
  #pragma unroll
  for (int k = 0; k < 4; ++k){
    int i = k*16 + ln;
    if (k < NC && i < deg) svk[k] = slot[start + i];
  }
  #pragma unroll
  for (int k = 0; k < 4; ++k){
    int i = k*16 + ln;
    if (k < NC && i < deg){
      float e = esg[svk[k]] + edv;
      sck[k] = e > 0.f ? e : 0.2f*e;
    }
  }
  float m = fmaxf(fmaxf(sck[0], sck[1]), fmaxf(sck[2], sck[3]));
  #pragma unroll
  for (int o = 8; o > 0; o >>= 1) m = fmaxf(m, __shfl_xor(m, o, 64));
  float exk[4]; float ssum = 0.f;
  #pragma unroll
  for (int k = 0; k < 4; ++k){
    int i = k*16 + ln;
    float e = (k < NC && i < deg) ? __expf(sck[k] - m) : 0.f;
    exk[k] = e; ssum += e;
  }
  #pragma unroll
  for (int o = 8; o > 0; o >>= 1) ssum += __shfl_xor(ssum, o, 64);
  float inv = fastrcp(ssum + 1e-16f);
  unsigned pwk[4];
  #pragma unroll
  for (int k = 0; k < 4; ++k)
    pwk[k] = (f2bf_rtn(exk[k]*inv) << 16) | (unsigned)svk[k];

  float a0 = 0.f, a1 = 0.f, a2 = 0.f, a3 = 0.f;
  for (int k = 0; k < NC; ++k){
    unsigned pw = pwk[k];
    int myrem = deg - k*16;                 // per-group remaining (predicate only)
    int remw = dm - k*16; if (remw > 16) remw = 16;   // wave-uniform trip
    for (int j0 = 0; j0 < remw; j0 += 8){
      unsigned wv[8]; float aa[8]; unsigned off[8];
      #pragma unroll
      for (int u = 0; u < 8; ++u){
        int j = j0 + u;
        wv[u] = (unsigned)__shfl((int)pw, hbase + j, 64);
        aa[u] = (j < myrem) ? uasf(wv[u] & 0xffff0000u) : 0.f;
        off[u] = ((wv[u] & 0xffffu) << 7) + lanoff;
      }
      uint2 hv[8];
      #pragma unroll
      for (int u = 0; u < 8; ++u)
        hv[u] = *(const uint2*)(hg + off[u]);
      #pragma unroll
      for (int u = 0; u < 8; ++u){
        a0 = fmaf(aa[u], uasf(hv[u].x << 16), a0);
        a1 = fmaf(aa[u], uasf(hv[u].x & 0xffff0000u), a1);
        a2 = fmaf(aa[u], uasf(hv[u].y << 16), a2);
        a3 = fmaf(aa[u], uasf(hv[u].y & 0xffff0000u), a3);
      }
    }
  }
  float4 bv = ((const float4*)bias)[ln];
  uint2 ov;
  ov.x = f2bf_rtn(gelu_exact(a0 + bv.x)) | (f2bf_rtn(gelu_exact(a1 + bv.y)) << 16);
  ov.y = f2bf_rtn(gelu_exact(a2 + bv.z)) | (f2bf_rtn(gelu_exact(a3 + bv.w)) << 16);
  ((uint2*)(goutb + (size_t)gd*H_))[ln] = ov;
}

// ---------- LSTM via MFMA + fused LN/dense ----------
// v3: throughput-attack on the gate math. 1000 blocks x 4 seqs: 256 threads ==
// 4 seqs x 64 units exactly, so each thread computes ONE (seq,unit) gate set per
// step (v2 computed 4 with half duplicated -> 4x the trans-pipe instructions).
// The per-thread row is runtime r=q (MFMA row 5q -> seq q): selected with 3
// v_cndmask per gate (sel4, static vector indices -> no scratch). A-operand
// rows are 4-way duplicated (seq = c&3) -- MFMA waste is free at ~5% MfmaUtil.
// ~4 blocks/CU -> each SIMD interleaves waves of 4 independent blocks.
// LDS strides: XSTRIDE=1568/HPAD=96 elems give quad=(4*cc+q)%8 -> <=2-way (free).
__global__ __launch_bounds__(256) void lstm_final_kernel(
    const unsigned short* __restrict__ xinb,  // bf16 flat [BN*T, 64]: row = seq*T + t
    const float* __restrict__ Wih,   // [256][64] row-major
    const float* __restrict__ Whh,   // [256][64] row-major
    const float* __restrict__ bih, const float* __restrict__ bhh,
    const float* __restrict__ lng, const float* __restrict__ lnb,
    const float* __restrict__ dW, const float* __restrict__ db,
    const int* __restrict__ flag, void* __restrict__ outv){
  __shared__ __align__(16) unsigned short Xlds[4*XSTRIDE];     // 12544 B
  __shared__ __align__(16) unsigned short Hlds[2][4*HPAD];     // 1536 B
  __shared__ float smH[4][68];       // +4 pad
  int tid = threadIdx.x;
  int lane = tid & 63, wave = tid >> 6;
  int q = lane >> 4, c = lane & 15;
  int cc = c & 3;                    // A-row seq (4 seqs/block, 4-way dup)
  int s0 = blockIdx.x * 4;

  // stage x: 4 seqs x 3072B contiguous from HBM -> padded LDS rows.
  // 12 chunks of 1KB; each wave takes 3; lane loads/stores 16B, fully coalesced.
  {
    const unsigned short* xg = xinb + (size_t)s0 * TH_;
    #pragma unroll
    for (int ch0 = 0; ch0 < 12; ch0 += 4){
      int ch = ch0 + wave;
      int r = ch / 3, jj = ch - r*3;
      bf16x8 v = *(const bf16x8*)(xg + r*1536 + jj*512 + lane*8);
      *(bf16x8*)(Xlds + r*XSTRIDE + jj*512 + lane*8) = v;
    }
  }

  bf16x8 Bf[4][4];
  #pragma unroll
  for (int g = 0; g < 4; ++g){
    int n = g*64 + wave*16 + c;
    #pragma unroll
    for (int ks = 0; ks < 4; ++ks){
      const float* srcp = (ks < 2) ? (Whh + (size_t)n*64 + ks*32 + q*8)
                                   : (Wih + (size_t)n*64 + (ks-2)*32 + q*8);
      float4 a = ((const float4*)srcp)[0];
      float4 b = ((const float4*)srcp)[1];
      Bf[g][ks] = pack8(a, b);
    }
  }
  float bsum[4];
  #pragma unroll
  for (int g = 0; g < 4; ++g){
    int n = g*64 + wave*16 + c;
    bsum[g] = bih[n] + bhh[n];
  }
  for (int i = tid; i < 4*HPAD; i += 256) Hlds[0][i] = 0;
  float cst = 0.f;                   // one (seq=q, unit=wave*16+c) state per thread
  __syncthreads();

  const unsigned short* xrow = Xlds + cc*XSTRIDE;
  bf16x8 Ax0 = *(const bf16x8*)(xrow + q*8);
  bf16x8 Ax1 = *(const bf16x8*)(xrow + 32 + q*8);

  int buf = 0;
  for (int t = 0; t < T_; ++t){
    const bf16x8* hrow = (const bf16x8*)(Hlds[buf] + cc*HPAD);
    bf16x8 Ah0 = hrow[0];
    bf16x8 Ah1 = hrow[4];
    // A-row = c reads seq c&3; hrow[q]? No: k-chunk select is q -> elements q*8.
    Ah0 = *(const bf16x8*)(Hlds[buf] + cc*HPAD + q*8);
    Ah1 = *(const bf16x8*)(Hlds[buf] + cc*HPAD + 32 + q*8);

    f32x4 acc[4];
    #pragma unroll
    for (int g = 0; g < 4; ++g){ acc[g][0]=bsum[g]; acc[g][1]=bsum[g]; acc[g][2]=bsum[g]; acc[g][3]=bsum[g]; }
    // x-MFMAs first (register operands, no wait), h-MFMAs last (hide ds_read)
    #pragma unroll
    for (int g = 0; g < 4; ++g) acc[g] = __builtin_amdgcn_mfma_f32_16x16x32_bf16(Ax0, Bf[g][2], acc[g], 0, 0, 0);
    #pragma unroll
    for (int g = 0; g < 4; ++g) acc[g] = __builtin_amdgcn_mfma_f32_16x16x32_bf16(Ax1, Bf[g][3], acc[g], 0, 0, 0);
    #pragma unroll
    for (int g = 0; g < 4; ++g) acc[g] = __builtin_amdgcn_mfma_f32_16x16x32_bf16(Ah0, Bf[g][0], acc[g], 0, 0, 0);
    #pragma unroll
    for (int g = 0; g < 4; ++g) acc[g] = __builtin_amdgcn_mfma_f32_16x16x32_bf16(Ah1, Bf[g][1], acc[g], 0, 0, 0);

    // prefetch next-step x from LDS (drained by the barrier's lgkmcnt(0))
    int tn = (t < T_-1) ? t+1 : T_-1;
    bf16x8 AxN0 = *(const bf16x8*)(xrow + tn*64 + q*8);
    bf16x8 AxN1 = *(const bf16x8*)(xrow + tn*64 + 32 + q*8);

    // this thread's row: MFMA row m = q*4 + q = 5q -> seq = m&3 = q. 1 gate set.
    float zi = sel4(acc[0], q), zf = sel4(acc[1], q), zg = sel4(acc[2], q), zo = sel4(acc[3], q);
    cst = sigf(zf)*cst + sigf(zi)*tanhfast(zg);
    float hv = sigf(zo)*tanhfast(cst);

    if (t == T_-1){
      smH[q][wave*16 + c] = hv;
    } else {
      Hlds[buf^1][q*HPAD + wave*16 + c] = (unsigned short)f2bf_rtn(hv);
      __syncthreads();
      buf ^= 1;
    }
    Ax0 = AxN0; Ax1 = AxN1;
  }
  __syncthreads();

  // fused LayerNorm + dense[64,12]; wave w handles seq s=w (4 seqs/block)
  int isbf = *flag;
  {
    int s = wave;
    float h = smH[s][lane];
    float mu = wave_sum(h) * (1.f/64.f);
    float dev = h - mu;
    float var = wave_sum(dev*dev) * (1.f/64.f);
    float hn = dev * rsqrtf(var + 1e-5f) * lng[lane] + lnb[lane];
    smH[s][lane] = hn;       // wave-internal write->read, in-order LDS
    if (lane < 12){
      float o = db[lane];
      #pragma unroll
      for (int k = 0; k < 64; ++k) o = fmaf(smH[s][k], dW[k*12 + lane], o);
      size_t oi = (size_t)(s0 + s)*12 + lane;
      if (isbf) ((unsigned short*)outv)[oi] = (unsigned short)f2bf_rtn(o);
      else      ((float*)outv)[oi] = o;
    }
  }
}

extern "C" void kernel_launch(void* const* d_in, const int* in_sizes, int n_in,
                              void* d_out, int out_size, void* d_ws, size_t ws_size,
                              hipStream_t stream) {
  const int* esrc = (const int*)d_in[1];
  const int* edst = (const int*)d_in[2];

  static const int sizes[18] = {512, 64, 4096, 64, 64, 64, 4096, 64, 64, 64,
                                16384, 16384, 256, 256, 64, 64, 768, 12};
  static const int srcidx[18] = {3, 4, 5, 6, 7, 8, 9, 10, 11, 12,
                                 13, 14, 15, 16, 17, 18, 19, 20};
  ConvArgs ca;
  {
    int acc = 0;
    for (int i = 0; i < 18; ++i){ ca.src[i] = d_in[srcidx[i]]; ca.off[i] = acc; acc += sizes[i]; }
    ca.off[18] = acc;   // == NPARAM_
  }

  float* P     = (float*)d_ws;               // [NPARAM_PAD_]
  float* bufA  = P + NPARAM_PAD_;            // gout (bf16, [GNH] ushort)
  float* bufB  = bufA + (size_t)GNH_/2 + 64; // hbuf(bf16)
  float* esb   = bufB + (size_t)GNH_/2 + 64;
  float* edb   = esb  + (size_t)G_*N_;
  int*   cnt_g = (int*)(edb + (size_t)G_*N_);// [N_]
  int*   slot  = cnt_g + N_;                 // [N_*64]
  int*   flag  = slot + N_*DEGCAP;           // [1]
  float* wcb   = (float*)(flag + 1);         // Wc[512] + bc[64]
  unsigned short* goutb = (unsigned short*)bufA;
  unsigned short* hbuf  = (unsigned short*)bufB;

  const float* pg1b = P + 4672;
  const float* pg1as= P + 4736;
  const float* pg1ad= P + 4800;
  const float* pg2W = P + 4864;
  const float* pg2b = P + 8960;
  const float* pg2as= P + 9024;
  const float* pg2ad= P + 9088;
  const float* pWih = P + 9152;
  const float* pWhh = P + 25536;
  const float* pbih = P + 41920;
  const float* pbhh = P + 42176;
  const float* plng = P + 42432;
  const float* plnb = P + 42496;
  const float* pdW  = P + 42560;
  const float* pdb  = P + 43328;

  prep_kernel<<<180, 256, 0, stream>>>(ca, (const unsigned*)d_in[0],
                                       P, flag, cnt_g, wcb, wcb + 512);

  gat_h1_fused_kernel<<<750, 256, 0, stream>>>(d_in[0], flag, esrc, edst, cnt_g, slot,
                                               wcb, wcb + 512, pg1as, pg1ad, hbuf, esb, edb);
  gat_agg_kernel<<<6000, 256, 0, stream>>>(hbuf, esb, edb, cnt_g, slot, pg1b, goutb);

  gat_h2_mfma_kernel<<<750, 256, 0, stream>>>(goutb, pg2W, pg2as, pg2ad, hbuf, esb, edb);
  gat_agg_kernel<<<6000, 256, 0, stream>>>(hbuf, esb, edb, cnt_g, slot, pg2b, goutb);

  lstm_final_kernel<<<1000, 256, 0, stream>>>(goutb, pWih, pWhh, pbih, pbhh,
                                              plng, plnb, pdW, pdb, flag, d_out);
}

// Round 5
// 214.836 us; speedup vs baseline: 1.0180x; 1.0180x over previous
//
#include <hip/hip_runtime.h>
#include <hip/hip_bf16.h>
#include <math.h>

#define B_   2
#define N_   2000
#define T_   24
#define NX_  8
#define H_   64
#define G_   (B_*T_)        // 48 graphs
#define E_   32000
#define BN_  (B_*N_)        // 4000 sequences
#define TH_  (T_*H_)        // 1536
#define NTH_ (N_*T_*H_)     // 3072000
#define GNH_ (G_*N_*H_)     // 6144000
#define NPARAM_ 43340       // canonical fp32 param elements (x excluded)
#define NPARAM_PAD_ 43392
#define XSTRIDE 1568        // per-seq x row (bf16 elems): 3136B stride, <=2-way banks
#define HPAD 96             // h row pad (bf16 elems): 192B stride, <=2-way banks
#define DEGCAP 64           // slot capacity per dst node (max binomial deg ~35)

using bf16 = __hip_bfloat16;
typedef short bf16x8 __attribute__((ext_vector_type(8)));
typedef float f32x4  __attribute__((ext_vector_type(4)));

__device__ __forceinline__ float uasf(unsigned u){ return __uint_as_float(u); }
__device__ __forceinline__ float wave_sum(float v){
  #pragma unroll
  for (int o = 32; o > 0; o >>= 1) v += __shfl_xor(v, o, 64);
  return v;
}
__device__ __forceinline__ float fastrcp(float x){ return __builtin_amdgcn_rcpf(x); }
__device__ __forceinline__ float sigf(float x){ return fastrcp(1.f + __expf(-x)); }
__device__ __forceinline__ float tanhfast(float x){ return 1.f - 2.f*fastrcp(1.f + __expf(2.f*x)); }
// exact-to-1.5e-7 gelu via A&S 7.1.26 erf (vs libm erff: ~half the instructions)
__device__ __forceinline__ float gelu_fast(float x){
  float s = x*0.70710678118654752f;
  float a = fabsf(s);
  float t = fastrcp(1.f + 0.3275911f*a);
  float p = t*(0.254829592f + t*(-0.284496736f + t*(1.421413741f + t*(-1.453152027f + t*1.061405429f))));
  float er = 1.f - p*__expf(-a*a);
  er = (s < 0.f) ? -er : er;
  return 0.5f*x*(1.f + er);
}
__device__ __forceinline__ unsigned f2bf_rtn(float f){
  unsigned u = __float_as_uint(f);
  u += 0x7fffu + ((u >> 16) & 1u);
  return u >> 16;
}
__device__ __forceinline__ bf16x8 pack8(float4 a, float4 b){
  bf16x8 v;
  v[0]=(short)f2bf_rtn(a.x); v[1]=(short)f2bf_rtn(a.y);
  v[2]=(short)f2bf_rtn(a.z); v[3]=(short)f2bf_rtn(a.w);
  v[4]=(short)f2bf_rtn(b.x); v[5]=(short)f2bf_rtn(b.y);
  v[6]=(short)f2bf_rtn(b.z); v[7]=(short)f2bf_rtn(b.w);
  return v;
}

// ---------- prep: dtype detect + param convert + cnt zero + Wc fold, ONE dispatch ----------
struct ConvArgs {
  const void* src[18];
  int off[19];
};
__global__ __launch_bounds__(256) void prep_kernel(
    ConvArgs a, const unsigned* __restrict__ xw,
    float* __restrict__ dst, int* __restrict__ flag,
    int* __restrict__ cnt_g,
    float* __restrict__ wc, float* __restrict__ bc){
  __shared__ int scnt;
  int tid = threadIdx.x;
  if (tid == 0) scnt = 0;
  __syncthreads();
  int c = 0;
  for (int i = tid; i < 4096; i += 256){
    unsigned e = (xw[i] >> 7) & 0xffu;
    if (e >= 100u && e <= 140u) c++;
  }
  atomicAdd(&scnt, c);
  __syncthreads();
  int isbf = (scnt > 3276) ? 1 : 0;
  int bid = blockIdx.x;

  if (bid < 170){
    if (bid == 0 && tid == 0) *flag = isbf;
    int i = bid*256 + tid;
    if (i < NPARAM_){
      int seg = 0;
      while (i >= a.off[seg+1]) seg++;
      int j = i - a.off[seg];
      float v;
      if (isbf) v = uasf(((unsigned)((const unsigned short*)a.src[seg])[j]) << 16);
      else      v = ((const float*)a.src[seg])[j];
      dst[i] = v;
    }
  } else if (bid == 170){
    for (int i = tid; i < N_; i += 256) cnt_g[i] = 0;
  } else {
    // blocks 171..179: Wc = fcW @ g1W (512 outs) + bc = fcb @ g1W (64 outs)
    int lane = tid & 63, wave = tid >> 6;
    int b = bid - 171;                   // 0..8
    const unsigned short* fcWu = (const unsigned short*)a.src[0];
    const unsigned short* fcbu = (const unsigned short*)a.src[1];
    const unsigned short* g1Wu = (const unsigned short*)a.src[2];
    const float* fcWf = (const float*)a.src[0];
    const float* fcbf = (const float*)a.src[1];
    const float* g1Wf = (const float*)a.src[2];
    #pragma unroll
    for (int s = 0; s < 16; ++s){
      int o = b*64 + wave*16 + s;        // 0..575
      int r = o >> 6;                    // 0..8 (8 == bias row)
      int n = o & 63;
      float fa, fb;
      if (isbf){
        fa = (r < 8) ? uasf(((unsigned)fcWu[r*64 + lane]) << 16)
                     : uasf(((unsigned)fcbu[lane]) << 16);
        fb = uasf(((unsigned)g1Wu[lane*64 + n]) << 16);
      } else {
        fa = (r < 8) ? fcWf[r*64 + lane] : fcbf[lane];
        fb = g1Wf[lane*64 + n];
      }
      float sv = wave_sum(fa * fb);
      if (lane == 0){
        if (r < 8) wc[r*64 + n] = sv;
        else       bc[n] = sv;
      }
    }
  }
}

// ---------- GAT1 fused: edge-table build (blocks 0..124) + h = x @ Wc + bc via MFMA ----------
__global__ __launch_bounds__(256) void gat_h1_fused_kernel(
    const void* __restrict__ xraw, const int* __restrict__ flag,
    const int* __restrict__ esrc, const int* __restrict__ edst,
    int* __restrict__ cnt_g, int* __restrict__ slot,
    const float* __restrict__ wc, const float* __restrict__ bc,
    const float* __restrict__ asrc, const float* __restrict__ adst,
    unsigned short* __restrict__ hbuf, float* __restrict__ es, float* __restrict__ ed){
  if (blockIdx.x < 125){
    int e = blockIdx.x*256 + threadIdx.x;      // exactly covers E_=32000
    int d = edst[e];
    int pos = atomicAdd(&cnt_g[d], 1);
    if (pos < DEGCAP) slot[(d << 6) + pos] = esrc[e];
  }
  int lane = threadIdx.x & 63, wave = threadIdx.x >> 6;
  int q = lane >> 4, c = lane & 15;
  int isbf = *flag;
  bf16x8 Bf[4];                       // B[n=c][k=q*8+j]; only q==0 rows of Wc nonzero
  #pragma unroll
  for (int nt = 0; nt < 4; ++nt){
    bf16x8 v;
    #pragma unroll
    for (int j = 0; j < 8; ++j)
      v[j] = (q == 0) ? (short)f2bf_rtn(wc[j*64 + nt*16 + c]) : (short)0;
    Bf[nt] = v;
  }
  float bcv[4];
  #pragma unroll
  for (int nt = 0; nt < 4; ++nt) bcv[nt] = bc[nt*16 + c];
  float aS[4], aD[4];
  #pragma unroll
  for (int nt = 0; nt < 4; ++nt){ aS[nt] = asrc[nt*16+c]; aD[nt] = adst[nt*16+c]; }

  int w = blockIdx.x*4 + wave;        // 750*4 = 3000 waves, 2 tiles each
  #pragma unroll
  for (int it = 0; it < 2; ++it){
    int tile = w*2 + it;
    int p0 = tile*16;
    int g  = p0 / N_, n0 = p0 - g*N_;
    int bb = g / T_,  tt = g - bb*T_;
    bf16x8 A0;
    #pragma unroll
    for (int j = 0; j < 8; ++j) A0[j] = 0;
    if (q == 0){
      size_t rowelt = ((size_t)(bb*N_ + n0 + c)*T_ + tt)*NX_;
      if (isbf){
        A0 = *(const bf16x8*)((const unsigned short*)xraw + rowelt);
      } else {
        const float4* xr4 = (const float4*)((const float*)xraw + rowelt);
        A0 = pack8(xr4[0], xr4[1]);
      }
    }
    f32x4 acc[4];
    #pragma unroll
    for (int nt = 0; nt < 4; ++nt){ acc[nt][0]=bcv[nt]; acc[nt][1]=bcv[nt]; acc[nt][2]=bcv[nt]; acc[nt][3]=bcv[nt]; }
    #pragma unroll
    for (int nt = 0; nt < 4; ++nt) acc[nt] = __builtin_amdgcn_mfma_f32_16x16x32_bf16(A0, Bf[nt], acc[nt], 0, 0, 0);

    #pragma unroll
    for (int nt = 0; nt < 4; ++nt){
      #pragma unroll
      for (int r = 0; r < 4; ++r)
        hbuf[(size_t)(p0 + q*4 + r)*H_ + nt*16 + c] = (unsigned short)f2bf_rtn(acc[nt][r]);
    }
    #pragma unroll
    for (int r = 0; r < 4; ++r){
      float e1 = acc[0][r]*aS[0] + acc[1][r]*aS[1] + acc[2][r]*aS[2] + acc[3][r]*aS[3];
      float e2 = acc[0][r]*aD[0] + acc[1][r]*aD[1] + acc[2][r]*aD[2] + acc[3][r]*aD[3];
      #pragma unroll
      for (int o = 8; o > 0; o >>= 1){
        e1 += __shfl_xor(e1, o, 64);
        e2 += __shfl_xor(e2, o, 64);
      }
      if (c == 0){
        es[p0 + q*4 + r] = e1;
        ed[p0 + q*4 + r] = e2;
      }
    }
  }
}

// ---------- GAT2 h = gout1(bf16) @ W via MFMA (scrambled raw-reshape reads) ----------
__global__ __launch_bounds__(256) void gat_h2_mfma_kernel(
    const unsigned short* __restrict__ xinb, const float* __restrict__ W,
    const float* __restrict__ asrc, const float* __restrict__ adst,
    unsigned short* __restrict__ hbuf, float* __restrict__ es, float* __restrict__ ed){
  int lane = threadIdx.x & 63, wave = threadIdx.x >> 6;
  int q = lane >> 4, c = lane & 15;
  bf16x8 Bf[4][2];
  #pragma unroll
  for (int nt = 0; nt < 4; ++nt){
    #pragma unroll
    for (int ks = 0; ks < 2; ++ks){
      bf16x8 v;
      #pragma unroll
      for (int j = 0; j < 8; ++j)
        v[j] = (short)f2bf_rtn(W[(ks*32 + q*8 + j)*H_ + nt*16 + c]);
      Bf[nt][ks] = v;
    }
  }
  float aS[4], aD[4];
  #pragma unroll
  for (int nt = 0; nt < 4; ++nt){ aS[nt] = asrc[nt*16+c]; aD[nt] = adst[nt*16+c]; }

  int w = blockIdx.x*4 + wave;
  #pragma unroll
  for (int it = 0; it < 2; ++it){
    int tile = w*2 + it;
    int p0 = tile*16;
    int p  = p0 + c;
    int g = p / N_, n = p - g*N_;
    int bb = g / T_, t = g - bb*T_;
    const unsigned short* xr = xinb + (size_t)bb*NTH_ + (size_t)n*TH_ + (size_t)t*H_;
    bf16x8 A0 = *(const bf16x8*)(xr + q*8);
    bf16x8 A1 = *(const bf16x8*)(xr + 32 + q*8);

    f32x4 acc[4];
    #pragma unroll
    for (int nt = 0; nt < 4; ++nt){ acc[nt][0]=0.f; acc[nt][1]=0.f; acc[nt][2]=0.f; acc[nt][3]=0.f; }
    #pragma unroll
    for (int nt = 0; nt < 4; ++nt) acc[nt] = __builtin_amdgcn_mfma_f32_16x16x32_bf16(A0, Bf[nt][0], acc[nt], 0, 0, 0);
    #pragma unroll
    for (int nt = 0; nt < 4; ++nt) acc[nt] = __builtin_amdgcn_mfma_f32_16x16x32_bf16(A1, Bf[nt][1], acc[nt], 0, 0, 0);

    #pragma unroll
    for (int nt = 0; nt < 4; ++nt){
      #pragma unroll
      for (int r = 0; r < 4; ++r)
        hbuf[(size_t)(p0 + q*4 + r)*H_ + nt*16 + c] = (unsigned short)f2bf_rtn(acc[nt][r]);
    }
    #pragma unroll
    for (int r = 0; r < 4; ++r){
      float e1 = acc[0][r]*aS[0] + acc[1][r]*aS[1] + acc[2][r]*aS[2] + acc[3][r]*aS[3];
      float e2 = acc[0][r]*aD[0] + acc[1][r]*aD[1] + acc[2][r]*aD[2] + acc[3][r]*aD[3];
      #pragma unroll
      for (int o = 8; o > 0; o >>= 1){
        e1 += __shfl_xor(e1, o, 64);
        e2 += __shfl_xor(e2, o, 64);
      }
      if (c == 0){
        es[p0 + q*4 + r] = e1;
        ed[p0 + q*4 + r] = e2;
      }
    }
  }
}

// ---------- GAT aggregate: 4 (g,d)/wave, 4 chan/lane uint2 gathers, bf16 output ----------
// v5 (= v4 arithmetic, non-template to match v3's known-good launch topology):
// no-max softmax (alpha invariant to max shift; scores O(1), exp clamped at 60 as
// overflow insurance) kills the fmax chain + 8-shfl max-reduce; gelu via
// A&S-7.1.26 erf (1.5e-7 exact) halves the libm erff instruction count.
__global__ __launch_bounds__(256) void gat_agg_kernel(
    const unsigned short* __restrict__ hbuf, const float* __restrict__ es, const float* __restrict__ ed,
    const int* __restrict__ cnt_g, const int* __restrict__ slot,
    const float* __restrict__ bias, unsigned short* __restrict__ goutb){
  int lane = threadIdx.x & 63, wave = threadIdx.x >> 6;
  int qd = lane >> 4, ln = lane & 15;
  int gd = (blockIdx.x*4 + wave)*4 + qd;   // 6000 blocks -> 96000 pairs
  int g = gd / N_, d = gd - g*N_;
  int start = d << 6;
  int deg = min(cnt_g[d], DEGCAP);
  const float* esg = es + (size_t)g*N_;
  float edv = ed[(size_t)g*N_ + d];
  const char* hg = (const char*)(hbuf + (size_t)g*N_*H_);
  unsigned lanoff = ((unsigned)ln) << 3;   // 8 B per lane = 4 bf16 channels
  int hbase = qd << 4;
  int dm = deg;                             // wave-uniform max degree over 4 groups
  dm = max(dm, __shfl_xor(dm, 16, 64));
  dm = max(dm, __shfl_xor(dm, 32, 64));
  int NC = (dm + 15) >> 4;                  // chunks of 16, <=4

  // pass 1: slot ids, then exp(lrelu(score)) directly (no max subtraction)
  int svk[4];
  #pragma unroll
  for (int k = 0; k < 4; ++k) svk[k] = 0;
  #pragma unroll
  for (int k = 0; k < 4; ++k){
    int i = k*16 + ln;
    if (k < NC && i < deg) svk[k] = slot[start + i];
  }
  float exk[4]; float ssum = 0.f;
  #pragma unroll
  for (int k = 0; k < 4; ++k){
    int i = k*16 + ln;
    float e = 0.f;
    if (k < NC && i < deg){
      float v = esg[svk[k]] + edv;
      v = v > 0.f ? v : 0.2f*v;
      e = __expf(fminf(v, 60.f));
    }
    exk[k] = e; ssum += e;
  }
  #pragma unroll
  for (int o = 8; o > 0; o >>= 1) ssum += __shfl_xor(ssum, o, 64);
  float inv = fastrcp(ssum + 1e-16f);
  unsigned pwk[4];
  #pragma unroll
  for (int k = 0; k < 4; ++k)
    pwk[k] = (f2bf_rtn(exk[k]*inv) << 16) | (unsigned)svk[k];

  // pass 2: gather h rows (uint2 = 4 channels) with shfl-broadcast ids
  float a0 = 0.f, a1 = 0.f, a2 = 0.f, a3 = 0.f;
  for (int k = 0; k < NC; ++k){
    unsigned pw = pwk[k];
    int myrem = deg - k*16;                 // per-group remaining (predicate only)
    int remw = dm - k*16; if (remw > 16) remw = 16;   // wave-uniform trip
    for (int j0 = 0; j0 < remw; j0 += 8){
      unsigned wv[8]; float aa[8]; unsigned off[8];
      #pragma unroll
      for (int u = 0; u < 8; ++u){
        int j = j0 + u;
        wv[u] = (unsigned)__shfl((int)pw, hbase + j, 64);
        aa[u] = (j < myrem) ? uasf(wv[u] & 0xffff0000u) : 0.f;
        off[u] = ((wv[u] & 0xffffu) << 7) + lanoff;
      }
      uint2 hv[8];
      #pragma unroll
      for (int u = 0; u < 8; ++u)
        hv[u] = *(const uint2*)(hg + off[u]);
      #pragma unroll
      for (int u = 0; u < 8; ++u){
        a0 = fmaf(aa[u], uasf(hv[u].x << 16), a0);
        a1 = fmaf(aa[u], uasf(hv[u].x & 0xffff0000u), a1);
        a2 = fmaf(aa[u], uasf(hv[u].y << 16), a2);
        a3 = fmaf(aa[u], uasf(hv[u].y & 0xffff0000u), a3);
      }
    }
  }
  float4 bv = ((const float4*)bias)[ln];
  uint2 ov;
  ov.x = f2bf_rtn(gelu_fast(a0 + bv.x)) | (f2bf_rtn(gelu_fast(a1 + bv.y)) << 16);
  ov.y = f2bf_rtn(gelu_fast(a2 + bv.z)) | (f2bf_rtn(gelu_fast(a3 + bv.w)) << 16);
  ((uint2*)(goutb + (size_t)gd*H_))[ln] = ov;
}

// ---------- LSTM via MFMA + fused LN/dense ----------
// v4: 1000 blocks x 4 seqs; A-row seq = c>>2 so MFMA row q*4+r has seq q for ALL
// r -> gate row is the STATIC acc[g][0] (sel4's 12 cndmask removed from the
// serial chain). x staged in LDS, next-step Ax prefetched, x-MFMAs before
// h-MFMAs to hide the post-barrier ds_read.
__global__ __launch_bounds__(256) void lstm_final_kernel(
    const unsigned short* __restrict__ xinb,  // bf16 flat [BN*T, 64]: row = seq*T + t
    const float* __restrict__ Wih,   // [256][64] row-major
    const float* __restrict__ Whh,   // [256][64] row-major
    const float* __restrict__ bih, const float* __restrict__ bhh,
    const float* __restrict__ lng, const float* __restrict__ lnb,
    const float* __restrict__ dW, const float* __restrict__ db,
    const int* __restrict__ flag, void* __restrict__ outv){
  __shared__ __align__(16) unsigned short Xlds[4*XSTRIDE];     // 12544 B
  __shared__ __align__(16) unsigned short Hlds[2][4*HPAD];     // 1536 B
  __shared__ float smH[4][68];       // +4 pad
  int tid = threadIdx.x;
  int lane = tid & 63, wave = tid >> 6;
  int q = lane >> 4, c = lane & 15;
  int cc = c >> 2;                   // A-row seq (4 seqs/block, 4-way dup, row-major groups)
  int s0 = blockIdx.x * 4;

  // stage x: 4 seqs x 3072B contiguous from HBM -> padded LDS rows.
  {
    const unsigned short* xg = xinb + (size_t)s0 * TH_;
    #pragma unroll
    for (int ch0 = 0; ch0 < 12; ch0 += 4){
      int ch = ch0 + wave;
      int r = ch / 3, jj = ch - r*3;
      bf16x8 v = *(const bf16x8*)(xg + r*1536 + jj*512 + lane*8);
      *(bf16x8*)(Xlds + r*XSTRIDE + jj*512 + lane*8) = v;
    }
  }

  bf16x8 Bf[4][4];
  #pragma unroll
  for (int g = 0; g < 4; ++g){
    int n = g*64 + wave*16 + c;
    #pragma unroll
    for (int ks = 0; ks < 4; ++ks){
      const float* srcp = (ks < 2) ? (Whh + (size_t)n*64 + ks*32 + q*8)
                                   : (Wih + (size_t)n*64 + (ks-2)*32 + q*8);
      float4 a = ((const float4*)srcp)[0];
      float4 b = ((const float4*)srcp)[1];
      Bf[g][ks] = pack8(a, b);
    }
  }
  float bsum[4];
  #pragma unroll
  for (int g = 0; g < 4; ++g){
    int n = g*64 + wave*16 + c;
    bsum[g] = bih[n] + bhh[n];
  }
  for (int i = tid; i < 4*HPAD; i += 256) Hlds[0][i] = 0;
  float cst = 0.f;                   // one (seq=q, unit=wave*16+c) state per thread
  __syncthreads();

  const unsigned short* xrow = Xlds + cc*XSTRIDE;
  bf16x8 Ax0 = *(const bf16x8*)(xrow + q*8);
  bf16x8 Ax1 = *(const bf16x8*)(xrow + 32 + q*8);

  int buf = 0;
  for (int t = 0; t < T_; ++t){
    bf16x8 Ah0 = *(const bf16x8*)(Hlds[buf] + cc*HPAD + q*8);
    bf16x8 Ah1 = *(const bf16x8*)(Hlds[buf] + cc*HPAD + 32 + q*8);

    f32x4 acc[4];
    #pragma unroll
    for (int g = 0; g < 4; ++g){ acc[g][0]=bsum[g]; acc[g][1]=bsum[g]; acc[g][2]=bsum[g]; acc[g][3]=bsum[g]; }
    // x-MFMAs first (register operands, no wait), h-MFMAs last (hide ds_read)
    #pragma unroll
    for (int g = 0; g < 4; ++g) acc[g] = __builtin_amdgcn_mfma_f32_16x16x32_bf16(Ax0, Bf[g][2], acc[g], 0, 0, 0);
    #pragma unroll
    for (int g = 0; g < 4; ++g) acc[g] = __builtin_amdgcn_mfma_f32_16x16x32_bf16(Ax1, Bf[g][3], acc[g], 0, 0, 0);
    #pragma unroll
    for (int g = 0; g < 4; ++g) acc[g] = __builtin_amdgcn_mfma_f32_16x16x32_bf16(Ah0, Bf[g][0], acc[g], 0, 0, 0);
    #pragma unroll
    for (int g = 0; g < 4; ++g) acc[g] = __builtin_amdgcn_mfma_f32_16x16x32_bf16(Ah1, Bf[g][1], acc[g], 0, 0, 0);

    // prefetch next-step x from LDS (drained by the barrier's lgkmcnt(0))
    int tn = (t < T_-1) ? t+1 : T_-1;
    bf16x8 AxN0 = *(const bf16x8*)(xrow + tn*64 + q*8);
    bf16x8 AxN1 = *(const bf16x8*)(xrow + tn*64 + 32 + q*8);

    // thread's row: MFMA rows q*4..q*4+3 all hold seq q -> static reg 0.
    float zi = acc[0][0], zf = acc[1][0], zg = acc[2][0], zo = acc[3][0];
    cst = sigf(zf)*cst + sigf(zi)*tanhfast(zg);
    float hv = sigf(zo)*tanhfast(cst);

    if (t == T_-1){
      smH[q][wave*16 + c] = hv;
    } else {
      Hlds[buf^1][q*HPAD + wave*16 + c] = (unsigned short)f2bf_rtn(hv);
      __syncthreads();
      buf ^= 1;
    }
    Ax0 = AxN0; Ax1 = AxN1;
  }
  __syncthreads();

  // fused LayerNorm + dense[64,12]; wave w handles seq s=w (4 seqs/block)
  int isbf = *flag;
  {
    int s = wave;
    float h = smH[s][lane];
    float mu = wave_sum(h) * (1.f/64.f);
    float dev = h - mu;
    float var = wave_sum(dev*dev) * (1.f/64.f);
    float hn = dev * rsqrtf(var + 1e-5f) * lng[lane] + lnb[lane];
    smH[s][lane] = hn;       // wave-internal write->read, in-order LDS
    if (lane < 12){
      float o = db[lane];
      #pragma unroll
      for (int k = 0; k < 64; ++k) o = fmaf(smH[s][k], dW[k*12 + lane], o);
      size_t oi = (size_t)(s0 + s)*12 + lane;
      if (isbf) ((unsigned short*)outv)[oi] = (unsigned short)f2bf_rtn(o);
      else      ((float*)outv)[oi] = o;
    }
  }
}

extern "C" void kernel_launch(void* const* d_in, const int* in_sizes, int n_in,
                              void* d_out, int out_size, void* d_ws, size_t ws_size,
                              hipStream_t stream) {
  const int* esrc = (const int*)d_in[1];
  const int* edst = (const int*)d_in[2];

  static const int sizes[18] = {512, 64, 4096, 64, 64, 64, 4096, 64, 64, 64,
                                16384, 16384, 256, 256, 64, 64, 768, 12};
  static const int srcidx[18] = {3, 4, 5, 6, 7, 8, 9, 10, 11, 12,
                                 13, 14, 15, 16, 17, 18, 19, 20};
  ConvArgs ca;
  {
    int acc = 0;
    for (int i = 0; i < 18; ++i){ ca.src[i] = d_in[srcidx[i]]; ca.off[i] = acc; acc += sizes[i]; }
    ca.off[18] = acc;   // == NPARAM_
  }

  float* P     = (float*)d_ws;               // [NPARAM_PAD_]
  float* bufA  = P + NPARAM_PAD_;            // gout (bf16, [GNH] ushort)
  float* bufB  = bufA + (size_t)GNH_/2 + 64; // hbuf(bf16)
  float* esb   = bufB + (size_t)GNH_/2 + 64;
  float* edb   = esb  + (size_t)G_*N_;
  int*   cnt_g = (int*)(edb + (size_t)G_*N_);// [N_]
  int*   slot  = cnt_g + N_;                 // [N_*64]
  int*   flag  = slot + N_*DEGCAP;           // [1]
  float* wcb   = (float*)(flag + 1);         // Wc[512] + bc[64]
  unsigned short* goutb = (unsigned short*)bufA;
  unsigned short* hbuf  = (unsigned short*)bufB;

  const float* pg1b = P + 4672;
  const float* pg1as= P + 4736;
  const float* pg1ad= P + 4800;
  const float* pg2W = P + 4864;
  const float* pg2b = P + 8960;
  const float* pg2as= P + 9024;
  const float* pg2ad= P + 9088;
  const float* pWih = P + 9152;
  const float* pWhh = P + 25536;
  const float* pbih = P + 41920;
  const float* pbhh = P + 42176;
  const float* plng = P + 42432;
  const float* plnb = P + 42496;
  const float* pdW  = P + 42560;
  const float* pdb  = P + 43328;

  prep_kernel<<<180, 256, 0, stream>>>(ca, (const unsigned*)d_in[0],
                                       P, flag, cnt_g, wcb, wcb + 512);

  gat_h1_fused_kernel<<<750, 256, 0, stream>>>(d_in[0], flag, esrc, edst, cnt_g, slot,
                                               wcb, wcb + 512, pg1as, pg1ad, hbuf, esb, edb);
  gat_agg_kernel<<<6000, 256, 0, stream>>>(hbuf, esb, edb, cnt_g, slot, pg1b, goutb);

  gat_h2_mfma_kernel<<<750, 256, 0, stream>>>(goutb, pg2W, pg2as, pg2ad, hbuf, esb, edb);
  gat_agg_kernel<<<6000, 256, 0, stream>>>(hbuf, esb, edb, cnt_g, slot, pg2b, goutb);

  lstm_final_kernel<<<1000, 256, 0, stream>>>(goutb, pWih, pWhh, pbih, pbhh,
                                              plng, plnb, pdW, pdb, flag, d_out);
}